// Round 13
// baseline (66.768 us; speedup 1.0000x reference)
//
#include <hip/hip_runtime.h>
#include <hip/hip_bf16.h>

// Problem constants
#define HEIGHT 480
#define WIDTH  640
#define IN_CH  6
#define CIN    8      // p, 1-p, 6 features
#define COUT   32
#define BATCH  8
#define NPTS   16384
#define NPTOT  (BATCH * NPTS)          // 131072 = 2^17
// Padded grid: rows 0..482 (point rows 1..481), cols 0..642 (point cols 1..641)
#define GH 483
#define GW 643
#define NCELLS ((size_t)BATCH * GH * GW)   // 2,484,552 cells
#define NWORDS 77644                       // ceil(NCELLS/32)=77643, +1 guard word

typedef float vfloat4 __attribute__((ext_vector_type(4)));  // native vec for nontemporal builtins

// grid layout: [b][gy][gx][cin], cin contiguous (32B per cell, 32B-aligned)
__device__ __forceinline__ size_t cell_idx(int b, int gy, int gx) {
    return ((size_t)b * GH + gy) * GW + gx;
}

__device__ __forceinline__ void point_cell(const float4 q, int point,
                                           int& b, int& gy, int& gx) {
    gy = (int)rintf(q.z * (float)HEIGHT) + 1;   // padded coord
    gx = (int)rintf(q.y * (float)WIDTH) + 1;
    b  = point >> 14;                           // NPTS = 16384
}

// Phase 0: zero both bitmask arrays (2*NWORDS u32 = 621 KB, contiguous).
__global__ void zero_masks_kernel(uint4* __restrict__ m4, int n4) {
    int i = blockIdx.x * blockDim.x + threadIdx.x;
    if (i < n4) m4[i] = make_uint4(0u, 0u, 0u, 0u);
}

// Phase 1: per point, set occupancy bit; on collision (bit already set) also
// set the multi bit AND zero the grid cell (idempotent - all colliders write
// identical zeros; value writes happen only in the next dispatch).
__global__ void count_kernel(const float4* __restrict__ xytp,
                             unsigned int* __restrict__ occ,
                             unsigned int* __restrict__ multi,
                             float* __restrict__ grid) {
    int point = blockIdx.x * blockDim.x + threadIdx.x;
    if (point >= NPTOT) return;
    float4 q = xytp[point];
    int b, gy, gx;
    point_cell(q, point, b, gy, gx);
    size_t ci = cell_idx(b, gy, gx);
    unsigned int word = (unsigned int)(ci >> 5);
    unsigned int bit  = 1u << (ci & 31);
    unsigned int old = atomicOr(&occ[word], bit);
    if (old & bit) {                                  // rare (~3%)
        atomicOr(&multi[word], bit);
        float* cell = grid + (ci << 3);
        const float4 z = make_float4(0.f, 0.f, 0.f, 0.f);
        *(float4*)(cell)     = z;
        *(float4*)(cell + 4) = z;
    }
}

// Phase 2: multi bit clear (~97%) -> plain 32B nontemporal store (skip RFO);
// else 8 f32 HW atomics into the cell count_kernel already zeroed.
__global__ void write_kernel(const float4* __restrict__ xytp,
                             const float*  __restrict__ feats,
                             const unsigned int* __restrict__ multi,
                             float* __restrict__ grid) {
    int point = blockIdx.x * blockDim.x + threadIdx.x;
    if (point >= NPTOT) return;
    float4 q = xytp[point];
    int b, gy, gx;
    point_cell(q, point, b, gy, gx);
    size_t ci = cell_idx(b, gy, gx);

    const float* f = feats + (size_t)point * IN_CH;
    float v0 = q.w, v1 = 1.0f - q.w;
    float f0 = f[0], f1 = f[1], f2 = f[2], f3 = f[3], f4 = f[4], f5 = f[5];

    unsigned int word = (unsigned int)(ci >> 5);
    unsigned int bit  = 1u << (ci & 31);

    float* cell = grid + (ci << 3);
    if (!(multi[word] & bit)) {
        vfloat4 a = {v0, v1, f0, f1};
        vfloat4 d = {f2, f3, f4, f5};
        __builtin_nontemporal_store(a, (vfloat4*)cell);
        __builtin_nontemporal_store(d, (vfloat4*)(cell + 4));
    } else {
        unsafeAtomicAdd(cell + 0, v0);
        unsafeAtomicAdd(cell + 1, v1);
        unsafeAtomicAdd(cell + 2, f0);
        unsafeAtomicAdd(cell + 3, f1);
        unsafeAtomicAdd(cell + 4, f2);
        unsafeAtomicAdd(cell + 5, f3);
        unsafeAtomicAdd(cell + 6, f4);
        unsafeAtomicAdd(cell + 7, f5);
    }
}

// Phase 3: 4 threads per point; sub s owns cells k in {s, s+4, s+8} (k<9).
// 2048 blocks -> 8 blocks/CU for latency hiding of the ~1.4 random gathers
// per point. Masked loads batch first, masked FMA second; partials combined
// by 2-step __shfl_xor butterfly (all register indices compile-time).
__global__ void __launch_bounds__(256)
conv_gather_kernel(const float4* __restrict__ xytp,
                   const float*  __restrict__ grid,
                   const unsigned int* __restrict__ occ,
                   const float*  __restrict__ W,     // [3][3][8][32]
                   const float*  __restrict__ bias,  // [32]
                   float* __restrict__ out) {
    int tid = blockIdx.x * blockDim.x + threadIdx.x;   // NPTOT*4 exact
    int point = tid >> 2;
    int sub   = tid & 3;                // 4 lanes share a point

    float4 q = xytp[point];
    int b, gy, gx;
    point_cell(q, point, b, gy, gx);
    size_t center  = cell_idx(b, gy, gx);
    size_t base_ci = center - GW - 1;   // padded window top-left

    // Occupancy bits for the 3x3 window (occ is 310KB -> cache-resident).
    unsigned int occ9 = 0;
#pragma unroll
    for (int ky = 0; ky < 3; ++ky) {
        size_t ci_row = base_ci + (size_t)ky * GW;
        size_t word = ci_row >> 5;
        int sh = (int)(ci_row & 31);
        unsigned long long two =
            (((unsigned long long)occ[word + 1]) << 32) | occ[word];
        occ9 |= ((unsigned int)(two >> sh) & 7u) << (ky * 3);
    }

    // Loads-only masked pass over my <=3 cells (one latency window).
    float4 g0[3], g1[3];
#pragma unroll
    for (int s = 0; s < 3; ++s) {
        int k = sub + 4 * s;
        if (k < 9 && (occ9 & (1u << k))) {
            size_t ci = base_ci + (size_t)(k / 3) * GW + (k % 3);
            const float* cell = grid + (ci << 3);
            g0[s] = *(const float4*)(cell);
            g1[s] = *(const float4*)(cell + 4);
        }
    }

    // Masked FMA pass.
    float acc[COUT];
#pragma unroll
    for (int c = 0; c < COUT; ++c) acc[c] = (sub == 0) ? bias[c] : 0.0f;

#pragma unroll
    for (int s = 0; s < 3; ++s) {
        int k = sub + 4 * s;
        if (k < 9 && (occ9 & (1u << k))) {
            float4 a = g0[s], d = g1[s];
            float gv[CIN] = {a.x, a.y, a.z, a.w, d.x, d.y, d.z, d.w};
            const float* wp = W + k * CIN * COUT;
#pragma unroll
            for (int ci2 = 0; ci2 < CIN; ++ci2) {
#pragma unroll
                for (int c = 0; c < COUT; ++c) {
                    acc[c] = fmaf(gv[ci2], wp[ci2 * COUT + c], acc[c]);
                }
            }
        }
    }

    // Butterfly reduce across the 4 subs (compile-time register indices).
    // Step 1 (xor 1): keep 16 channels selected by sub bit0.
    float h[16];
#pragma unroll
    for (int c = 0; c < 16; ++c) {
        float mine  = (sub & 1) ? acc[16 + c] : acc[c];
        float other = (sub & 1) ? acc[c]      : acc[16 + c];
        h[c] = mine + __shfl_xor(other, 1);
    }
    // Step 2 (xor 2): keep 8 channels selected by sub bit1.
    float r[8];
#pragma unroll
    for (int c = 0; c < 8; ++c) {
        float mine  = (sub & 2) ? h[8 + c] : h[c];
        float other = (sub & 2) ? h[c]     : h[8 + c];
        r[c] = mine + __shfl_xor(other, 2);
    }

    // Final channel base: sub 0->0, 1->16, 2->8, 3->24 (covers 0..31 per point).
    int cbase = (sub & 1) * 16 + (sub & 2) * 4;
    float* o = out + (size_t)point * COUT + cbase;
    *(float4*)(o)     = make_float4(r[0], r[1], r[2], r[3]);
    *(float4*)(o + 4) = make_float4(r[4], r[5], r[6], r[7]);
}

extern "C" void kernel_launch(void* const* d_in, const int* in_sizes, int n_in,
                              void* d_out, int out_size, void* d_ws, size_t ws_size,
                              hipStream_t stream) {
    const float4* xytp  = (const float4*)d_in[0];   // (8,16384,4)
    const float*  feats = (const float*)d_in[1];    // (8,16384,6)
    const float*  W     = (const float*)d_in[2];    // (3,3,8,32)
    const float*  bias  = (const float*)d_in[3];    // (32,)
    float* out = (float*)d_out;                     // (8,16384,32)

    float* grid = (float*)d_ws;                     // 79.5 MB (f32 cells)
    const size_t grid_bytes = NCELLS * CIN * sizeof(float);
    unsigned int* occ   = (unsigned int*)((char*)d_ws + grid_bytes);
    unsigned int* multi = occ + NWORDS;
    (void)ws_size;

    const int blk = 256;
    const int nblk_pts = (NPTOT + blk - 1) / blk;   // 512

    const int n4 = (2 * NWORDS) / 4;                // 38,822 uint4
    zero_masks_kernel<<<(n4 + blk - 1) / blk, blk, 0, stream>>>((uint4*)occ, n4);

    count_kernel<<<nblk_pts, blk, 0, stream>>>(xytp, occ, multi, grid);

    write_kernel<<<nblk_pts, blk, 0, stream>>>(xytp, feats, multi, grid);

    conv_gather_kernel<<<(NPTOT * 4) / blk, blk, 0, stream>>>(xytp, grid, occ, W, bias, out);
}

// Round 14
// 41.955 us; speedup vs baseline: 1.5914x; 1.5914x over previous
//
#include <hip/hip_runtime.h>
#include <hip/hip_bf16.h>

// Problem constants
#define HEIGHT 480
#define WIDTH  640
#define IN_CH  6
#define CIN    8      // p, 1-p, 6 features
#define COUT   32
#define BATCH  8
#define NPTS   16384
#define NPTOT  (BATCH * NPTS)          // 131072 = 2^17
// Padded grid: rows 0..482 (point rows 1..481), cols 0..642 (point cols 1..641)
#define GH 483
#define GW 643
#define NCELLS ((size_t)BATCH * GH * GW)   // 2,484,552 cells
#define NW64   38824                       // ceil(NCELLS/64)=38822 +guard, even

typedef float vfloat4 __attribute__((ext_vector_type(4)));  // for nontemporal stores

// grid layout: [b][gy][gx][cin], cin contiguous (32B per cell, 32B-aligned)
__device__ __forceinline__ size_t cell_idx(int b, int gy, int gx) {
    return ((size_t)b * GH + gy) * GW + gx;
}

__device__ __forceinline__ void point_cell(const float4 q, int point,
                                           int& b, int& gy, int& gx) {
    gy = (int)rintf(q.z * (float)HEIGHT) + 1;   // padded coord
    gx = (int)rintf(q.y * (float)WIDTH) + 1;
    b  = point >> 14;                           // NPTS = 16384
}

// Phase 0: zero both u64 bitmask arrays (2*NW64*8 B = 621 KB, contiguous).
__global__ void zero_masks_kernel(uint4* __restrict__ m4, int n4) {
    int i = blockIdx.x * blockDim.x + threadIdx.x;
    if (i < n4) m4[i] = make_uint4(0u, 0u, 0u, 0u);
}

// Phase 1: per point, set occupancy bit (u64 atomicOr); on collision also set
// multi bit AND zero the grid cell (idempotent - colliders write identical
// zeros; value writes happen only in the next dispatch).
__global__ void count_kernel(const float4* __restrict__ xytp,
                             unsigned long long* __restrict__ occ,
                             unsigned long long* __restrict__ multi,
                             float* __restrict__ grid) {
    int point = blockIdx.x * blockDim.x + threadIdx.x;
    if (point >= NPTOT) return;
    float4 q = xytp[point];
    int b, gy, gx;
    point_cell(q, point, b, gy, gx);
    size_t ci = cell_idx(b, gy, gx);
    size_t word = ci >> 6;
    unsigned long long bit = 1ull << (ci & 63);
    unsigned long long old = atomicOr(&occ[word], bit);
    if (old & bit) {                                  // rare (~3%)
        atomicOr(&multi[word], bit);
        float* cell = grid + (ci << 3);
        const float4 z = make_float4(0.f, 0.f, 0.f, 0.f);
        *(float4*)(cell)     = z;
        *(float4*)(cell + 4) = z;
    }
}

// Phase 2: multi bit clear (~97%) -> 32B nontemporal store (skip RFO);
// else 8 f32 HW atomics into the cell count_kernel already zeroed.
__global__ void write_kernel(const float4* __restrict__ xytp,
                             const float*  __restrict__ feats,
                             const unsigned long long* __restrict__ multi,
                             float* __restrict__ grid) {
    int point = blockIdx.x * blockDim.x + threadIdx.x;
    if (point >= NPTOT) return;
    float4 q = xytp[point];
    int b, gy, gx;
    point_cell(q, point, b, gy, gx);
    size_t ci = cell_idx(b, gy, gx);

    const float* f = feats + (size_t)point * IN_CH;
    float v0 = q.w, v1 = 1.0f - q.w;
    float f0 = f[0], f1 = f[1], f2 = f[2], f3 = f[3], f4 = f[4], f5 = f[5];

    float* cell = grid + (ci << 3);
    if (!((multi[ci >> 6] >> (ci & 63)) & 1ull)) {
        vfloat4 a = {v0, v1, f0, f1};
        vfloat4 d = {f2, f3, f4, f5};
        __builtin_nontemporal_store(a, (vfloat4*)cell);
        __builtin_nontemporal_store(d, (vfloat4*)(cell + 4));
    } else {
        unsafeAtomicAdd(cell + 0, v0);
        unsafeAtomicAdd(cell + 1, v1);
        unsafeAtomicAdd(cell + 2, f0);
        unsafeAtomicAdd(cell + 3, f1);
        unsafeAtomicAdd(cell + 4, f2);
        unsafeAtomicAdd(cell + 5, f3);
        unsafeAtomicAdd(cell + 6, f4);
        unsafeAtomicAdd(cell + 7, f5);
    }
}

// Phase 3: 1 thread per point. Random-transaction budget per point:
// 3 u64 occ-row loads (+3% straddle) + ~2.84 masked cell float4-pairs.
// All masked loads batch in one latency window, then masked FMA pass.
__global__ void __launch_bounds__(256)
conv_gather_kernel(const float4* __restrict__ xytp,
                   const float*  __restrict__ grid,
                   const unsigned long long* __restrict__ occ,
                   const float*  __restrict__ W,     // [3][3][8][32]
                   const float*  __restrict__ bias,  // [32]
                   float* __restrict__ out) {
    int point = blockIdx.x * blockDim.x + threadIdx.x;
    if (point >= NPTOT) return;
    float4 q = xytp[point];
    int b, gy, gx;
    point_cell(q, point, b, gy, gx);
    size_t center  = cell_idx(b, gy, gx);
    size_t base_ci = center - GW - 1;   // padded window top-left

    // Occupancy bits: one aligned u64 load per row (straddle load ~3%/row).
    unsigned int occ9 = 0;
#pragma unroll
    for (int ky = 0; ky < 3; ++ky) {
        size_t ci_row = base_ci + (size_t)ky * GW;
        size_t w  = ci_row >> 6;
        int    sh = (int)(ci_row & 63);
        unsigned long long v = occ[w] >> sh;
        if (sh >= 62) v |= occ[w + 1] << (64 - sh);
        occ9 |= ((unsigned int)v & 7u) << (ky * 3);
    }

    // Loads-only masked pass (all occupied-cell loads in one latency window).
    float4 g0[9], g1[9];
#pragma unroll
    for (int k = 0; k < 9; ++k) {
        if (occ9 & (1u << k)) {
            size_t ci = base_ci + (size_t)(k / 3) * GW + (k % 3);
            const float* cell = grid + (ci << 3);
            g0[k] = *(const float4*)(cell);
            g1[k] = *(const float4*)(cell + 4);
        }
    }

    // Masked FMA pass.
    float acc[COUT];
#pragma unroll
    for (int c = 0; c < COUT; ++c) acc[c] = bias[c];

#pragma unroll
    for (int k = 0; k < 9; ++k) {
        if (occ9 & (1u << k)) {
            float4 a = g0[k], d = g1[k];
            float gv[CIN] = {a.x, a.y, a.z, a.w, d.x, d.y, d.z, d.w};
            const float* wp = W + k * CIN * COUT;
#pragma unroll
            for (int ci2 = 0; ci2 < CIN; ++ci2) {
#pragma unroll
                for (int c = 0; c < COUT; ++c) {
                    acc[c] = fmaf(gv[ci2], wp[ci2 * COUT + c], acc[c]);
                }
            }
        }
    }

    float* o = out + (size_t)point * COUT;
#pragma unroll
    for (int c = 0; c < COUT; c += 4) {
        *(float4*)(o + c) = make_float4(acc[c], acc[c + 1], acc[c + 2], acc[c + 3]);
    }
}

extern "C" void kernel_launch(void* const* d_in, const int* in_sizes, int n_in,
                              void* d_out, int out_size, void* d_ws, size_t ws_size,
                              hipStream_t stream) {
    const float4* xytp  = (const float4*)d_in[0];   // (8,16384,4)
    const float*  feats = (const float*)d_in[1];    // (8,16384,6)
    const float*  W     = (const float*)d_in[2];    // (3,3,8,32)
    const float*  bias  = (const float*)d_in[3];    // (32,)
    float* out = (float*)d_out;                     // (8,16384,32)

    float* grid = (float*)d_ws;                     // 79.5 MB (f32 cells)
    const size_t grid_bytes = NCELLS * CIN * sizeof(float);
    unsigned long long* occ   = (unsigned long long*)((char*)d_ws + grid_bytes);
    unsigned long long* multi = occ + NW64;
    (void)ws_size;

    const int blk = 256;
    const int nblk_pts = (NPTOT + blk - 1) / blk;   // 512

    const int n4 = (2 * NW64 * 8) / 16;             // 38,824 uint4
    zero_masks_kernel<<<(n4 + blk - 1) / blk, blk, 0, stream>>>((uint4*)occ, n4);

    count_kernel<<<nblk_pts, blk, 0, stream>>>(xytp, occ, multi, grid);

    write_kernel<<<nblk_pts, blk, 0, stream>>>(xytp, feats, multi, grid);

    conv_gather_kernel<<<nblk_pts, blk, 0, stream>>>(xytp, grid, occ, W, bias, out);
}